// Round 5
// baseline (61.579 us; speedup 1.0000x reference)
//
#include <hip/hip_runtime.h>
#include <math.h>

// IN_C=3, DIM=256, OUT_C=256, N_PIECES=20, BATCH=16, SET_N=128

#if __has_builtin(__builtin_amdgcn_exp2f)
#define EXP2F(x) __builtin_amdgcn_exp2f(x)
#else
#define EXP2F(x) exp2f(x)
#endif

// ---------------------------------------------------------------------------
// K1: fused conv1+conv2. Tile 16 d x 64 bn, grid (32, 16) = 512 blocks.
// (unchanged from R4 to isolate fspool delta)
// ---------------------------------------------------------------------------
__global__ __launch_bounds__(256) void conv12_kernel(
    const float* __restrict__ x, const float* __restrict__ w1,
    const float* __restrict__ b1, const float* __restrict__ W2,
    const float* __restrict__ b2, float* __restrict__ H2)
{
    __shared__ float xs[3][64];
    __shared__ float As[16][16];
    __shared__ float Bs[16][64];

    int tid = threadIdx.x;
    int bx  = blockIdx.x;
    int d0  = blockIdx.y * 16;
    int b   = bx >> 1;
    int n0  = (bx & 1) * 64;

    if (tid < 192) {
        int c = tid >> 6, n = tid & 63;
        xs[c][n] = x[b * 384 + c * 128 + n0 + n];
    }
    __syncthreads();

    int tx = tid & 15, ty = tid >> 4;
    float acc[4] = {};

    for (int k0 = 0; k0 < 256; k0 += 16) {
        {
            int dl = tid & 15, kk = tid >> 4;
            As[kk][dl] = W2[(d0 + dl) * 256 + k0 + kk];
        }
        #pragma unroll
        for (int q = 0; q < 4; q++) {
            int idx = q * 256 + tid;
            int krel = idx >> 6, nl = idx & 63;
            int k = k0 + krel;
            float h = fmaf(w1[k * 3 + 0], xs[0][nl],
                      fmaf(w1[k * 3 + 1], xs[1][nl],
                      fmaf(w1[k * 3 + 2], xs[2][nl], b1[k])));
            Bs[krel][nl] = fmaxf(h, 0.0f);
        }
        __syncthreads();
        #pragma unroll
        for (int kk = 0; kk < 16; kk++) {
            float a  = As[kk][ty];
            float4 bv = *(const float4*)(&Bs[kk][tx * 4]);
            acc[0] = fmaf(a, bv.x, acc[0]);
            acc[1] = fmaf(a, bv.y, acc[1]);
            acc[2] = fmaf(a, bv.z, acc[2]);
            acc[3] = fmaf(a, bv.w, acc[3]);
        }
        __syncthreads();
    }

    int d = d0 + ty;
    float bias = b2[d];
    float4 o = make_float4(acc[0] + bias, acc[1] + bias,
                           acc[2] + bias, acc[3] + bias);
    *(float4*)(H2 + b * 32768 + d * 128 + n0 + tx * 4) = o;
}

// ---------------------------------------------------------------------------
__device__ __forceinline__ float pool_weight(const float* __restrict__ pw, int j)
{
    float ratio = (float)j / 127.0f;
    float idx_f = 20.0f * ratio;
    int idx = (int)idx_f;
    float frac = idx_f - (float)idx;
    int idx2 = idx + 1 > 20 ? 20 : idx + 1;
    return (1.0f - frac) * pw[idx] + frac * pw[idx2];
}

// ---------------------------------------------------------------------------
// K2: FSPool v3. ONE wave per row, 2 j per lane (j = l, l+64).
// Packed LDS float2 (s_i, B_i*log2e): one ds_read_b128 = 2 i-elements
// serving both j's -> 160 LDS instrs/row (half of R4's 320).
// Block = 4 waves = 4 rows; grid 1024.
// ---------------------------------------------------------------------------
__global__ __launch_bounds__(256) void fspool_kernel(
    const float* __restrict__ s_glob,    // [4096][128]
    const float* __restrict__ pool_w,    // [256][21]
    float* __restrict__ pooled)          // [4096]
{
    const float LOG2E = 1.4426950408889634f;
    __shared__ __align__(16) float  ss[4][128];
    __shared__ __align__(16) float2 sb[4][128];

    int tid = threadIdx.x;
    int w   = tid >> 6;          // row-local wave
    int l   = tid & 63;
    int row = blockIdx.x * 4 + w;

    // stage s row (wave reads 512 contiguous bytes)
    float2 sv = *(const float2*)(s_glob + row * 128 + l * 2);
    *(float2*)(&ss[w][l * 2]) = sv;
    __syncthreads();

    // ---- Bsum for own i0=l, i1=l+64 ----
    float si0 = ss[w][l];
    float si1 = ss[w][l + 64];
    float a0 = 0.f, a1 = 0.f, a2 = 0.f, a3 = 0.f;
    float c0 = 0.f, c1 = 0.f, c2 = 0.f, c3 = 0.f;
    #pragma unroll 4
    for (int j = 0; j < 128; j += 4) {
        float4 s4 = *(const float4*)(&ss[w][j]);
        a0 += fabsf(si0 - s4.x);
        a1 += fabsf(si0 - s4.y);
        a2 += fabsf(si0 - s4.z);
        a3 += fabsf(si0 - s4.w);
        c0 += fabsf(si1 - s4.x);
        c1 += fabsf(si1 - s4.y);
        c2 += fabsf(si1 - s4.z);
        c3 += fabsf(si1 - s4.w);
    }
    float B0 = ((a0 + a1) + (a2 + a3)) * LOG2E;
    float B1 = ((c0 + c1) + (c2 + c3)) * LOG2E;
    sb[w][l]      = make_float2(si0, B0);
    sb[w][l + 64] = make_float2(si1, B1);
    __syncthreads();

    // ---- softmax for j0 = l, j1 = l+64 (log2 domain) ----
    float scal0 = (float)(127 - 2 * l) * LOG2E;
    float scal1 = (float)(127 - 2 * (l + 64)) * LOG2E;

    float m00 = -1e30f, m01 = -1e30f, m10 = -1e30f, m11 = -1e30f;
    #pragma unroll 4
    for (int i = 0; i < 128; i += 2) {
        float4 p = *(const float4*)(&sb[w][i]);   // (s_i,b_i,s_i1,b_i1)
        m00 = fmaxf(m00, fmaf(p.x, scal0, -p.y));
        m01 = fmaxf(m01, fmaf(p.z, scal0, -p.w));
        m10 = fmaxf(m10, fmaf(p.x, scal1, -p.y));
        m11 = fmaxf(m11, fmaf(p.z, scal1, -p.w));
    }
    float m0 = fmaxf(m00, m01), m1 = fmaxf(m10, m11);

    float se0a = 0.f, se0b = 0.f, sd0a = 0.f, sd0b = 0.f;
    float se1a = 0.f, se1b = 0.f, sd1a = 0.f, sd1b = 0.f;
    #pragma unroll 4
    for (int i = 0; i < 128; i += 2) {
        float4 p = *(const float4*)(&sb[w][i]);
        float e0a = EXP2F(fmaf(p.x, scal0, -p.y) - m0);
        float e0b = EXP2F(fmaf(p.z, scal0, -p.w) - m0);
        float e1a = EXP2F(fmaf(p.x, scal1, -p.y) - m1);
        float e1b = EXP2F(fmaf(p.z, scal1, -p.w) - m1);
        se0a += e0a; sd0a = fmaf(e0a, p.x, sd0a);
        se0b += e0b; sd0b = fmaf(e0b, p.z, sd0b);
        se1a += e1a; sd1a = fmaf(e1a, p.x, sd1a);
        se1b += e1b; sd1b = fmaf(e1b, p.z, sd1b);
    }
    float xs0 = (sd0a + sd0b) / (se0a + se0b);
    float xs1 = (sd1a + sd1b) / (se1a + se1b);

    int c = row & 255;
    const float* pw = pool_w + c * 21;
    float part = xs0 * pool_weight(pw, l) + xs1 * pool_weight(pw, l + 64);

    #pragma unroll
    for (int off = 32; off > 0; off >>= 1)
        part += __shfl_xor(part, off);
    if (l == 0) pooled[row] = part;
}

// ---------------------------------------------------------------------------
// K3: fused MLP tail (unchanged).
// ---------------------------------------------------------------------------
__device__ __forceinline__ void dense1024(
    const float* __restrict__ W, const float* __restrict__ Bv,
    const float* in_lds, float* out_lds, int tid, bool do_relu)
{
    int o = tid >> 2, p = tid & 3;
    const float* wr = W + o * 256 + p * 64;
    const float* ir = in_lds + p * 64;
    float acc = 0.0f;
    #pragma unroll
    for (int k = 0; k < 64; k += 4) {
        float4 wv = *(const float4*)(wr + k);
        float4 iv = *(const float4*)(ir + k);
        acc = fmaf(wv.x, iv.x, acc);
        acc = fmaf(wv.y, iv.y, acc);
        acc = fmaf(wv.z, iv.z, acc);
        acc = fmaf(wv.w, iv.w, acc);
    }
    acc += __shfl_xor(acc, 1);
    acc += __shfl_xor(acc, 2);
    if (p == 0) {
        acc += Bv[o];
        out_lds[o] = do_relu ? fmaxf(acc, 0.0f) : acc;
    }
}

__global__ __launch_bounds__(1024) void tail_kernel(
    const float* __restrict__ pooled,
    const float* __restrict__ W1, const float* __restrict__ B1,
    const float* __restrict__ W2, const float* __restrict__ B2,
    const float* __restrict__ W3, const float* __restrict__ B3,
    const float* __restrict__ W4, const float* __restrict__ B4,
    float* __restrict__ out)
{
    __shared__ float za[256], zb[256];
    int b = blockIdx.x, tid = threadIdx.x;
    if (tid < 256) za[tid] = pooled[b * 256 + tid];
    __syncthreads();
    dense1024(W1, B1, za, zb, tid, true);
    __syncthreads();
    dense1024(W2, B2, zb, za, tid, false);
    __syncthreads();
    dense1024(W3, B3, za, zb, tid, true);
    __syncthreads();
    if (tid < 640) {
        int o = tid >> 6, kb = tid & 63;
        float4 wv = *(const float4*)(W4 + o * 256 + kb * 4);
        float4 zv = *(const float4*)(zb + kb * 4);
        float p = fmaf(wv.x, zv.x, fmaf(wv.y, zv.y,
                  fmaf(wv.z, zv.z, wv.w * zv.w)));
        #pragma unroll
        for (int off = 32; off > 0; off >>= 1)
            p += __shfl_xor(p, off);
        if (kb == 0) out[b * 10 + o] = p + B4[o];
    }
}

// ---------------------------------------------------------------------------
extern "C" void kernel_launch(void* const* d_in, const int* in_sizes, int n_in,
                              void* d_out, int out_size, void* d_ws, size_t ws_size,
                              hipStream_t stream)
{
    (void)in_sizes; (void)n_in; (void)out_size; (void)ws_size;
    const float* x       = (const float*)d_in[0];
    const float* conv1_w = (const float*)d_in[1];
    const float* conv1_b = (const float*)d_in[2];
    const float* conv2_w = (const float*)d_in[3];
    const float* conv2_b = (const float*)d_in[4];
    const float* pool_w  = (const float*)d_in[5];
    const float* lin1_w  = (const float*)d_in[6];
    const float* lin1_b  = (const float*)d_in[7];
    const float* lin2_w  = (const float*)d_in[8];
    const float* lin2_b  = (const float*)d_in[9];
    const float* cls1_w  = (const float*)d_in[10];
    const float* cls1_b  = (const float*)d_in[11];
    const float* cls2_w  = (const float*)d_in[12];
    const float* cls2_b  = (const float*)d_in[13];
    float* out = (float*)d_out;

    float* ws     = (float*)d_ws;
    float* H2     = ws;                 // 524288 floats
    float* pooled = ws + 524288;        // 4096 floats

    conv12_kernel<<<dim3(32, 16), 256, 0, stream>>>(x, conv1_w, conv1_b,
                                                    conv2_w, conv2_b, H2);
    fspool_kernel<<<1024, 256, 0, stream>>>(H2, pool_w, pooled);
    tail_kernel<<<16, 1024, 0, stream>>>(pooled,
        lin1_w, lin1_b, lin2_w, lin2_b, cls1_w, cls1_b, cls2_w, cls2_b, out);
}